// Round 13
// baseline (1216.625 us; speedup 1.0000x reference)
//
#include <hip/hip_runtime.h>
#include <hip/hip_bf16.h>

// R13 — MEASUREMENT ROUND: identical R12 pipeline launched TWICE (idempotent).
// dur_R13 - dur_R12 = total time of my 4 kernels (K), separating kernel time
// from the harness's fixed reset overhead (2.1 GB ws poison + d_in restores).

#define BN      32768   // B*N rows
#define NCOL    4096    // N
#define MAX_NBR 64      // Binomial(4096,0.004): mean 16.4, P(deg>64) ~ 1e-19

#define WS_NBR 0                       // u16 [BN][64]   (4 MB)
#define WS_DEG (4*1024*1024)           // int [BN]       (128 KB)
#define WS_H0  (WS_DEG + 131072)       // f32 [BN][64]   (8 MB)
#define WS_H1  (WS_H0 + 8*1024*1024)   // f32 [BN][32]   (4 MB)

__global__ __launch_bounds__(256) void build_csr_kernel(
    const float* __restrict__ adj,
    unsigned short* __restrict__ nbr,
    int* __restrict__ deg)
{
    const int wave = threadIdx.x >> 6, lane = threadIdx.x & 63;
    const int row  = (blockIdx.x << 2) + wave;
    const float4* arow = reinterpret_cast<const float4*>(adj + (size_t)row * NCOL);
    unsigned short* outrow = nbr + (size_t)row * MAX_NBR;
    const unsigned long long below = (1ull << lane) - 1ull;

    int cnt = 0;
    #pragma unroll 4
    for (int t = 0; t < 16; ++t) {
        const int c = t * 64 + lane;
        const float4 q = arow[c];
        const float v[4] = { q.x, q.y, q.z, q.w };
        #pragma unroll
        for (int e = 0; e < 4; ++e) {
            const bool nz = (v[e] != 0.0f);
            const unsigned long long m = __ballot(nz);
            if (nz) {
                const int pos = cnt + (int)__popcll(m & below);
                if (pos < MAX_NBR) outrow[pos] = (unsigned short)(c * 4 + e);
            }
            cnt += (int)__popcll(m);
        }
    }
    if (lane == 0) deg[row] = cnt;
}

template<int D_IN, int D_OUT>
__global__ __launch_bounds__(256) void gather_layer_kernel(
    const float* __restrict__ hin,
    const unsigned short* __restrict__ nbr,
    const int* __restrict__ deg,
    const float* __restrict__ Ws, const float* __restrict__ Wn,
    const float* __restrict__ bias,
    float* __restrict__ hout)
{
    constexpr int SUB = (D_IN >= 64) ? 1 : (64 / D_IN);
    constexpr int KPL = (D_IN + 63) / 64;
    constexpr int NW  = 4 * SUB;
    __shared__ float s_self[D_IN];
    __shared__ float s_part[NW][D_IN];
    __shared__ float s_neigh[D_IN];

    const int tid  = threadIdx.x;
    const int wave = tid >> 6, lane = tid & 63;
    const int sub  = (D_IN < 64) ? (lane / D_IN) : 0;
    const int sl   = (D_IN < 64) ? (lane % D_IN) : lane;
    const int strm = wave * SUB + sub;
    const int row  = blockIdx.x;
    const int jbase = row & ~(NCOL - 1);

    const int d   = deg[row];
    const int cnt = d < MAX_NBR ? d : MAX_NBR;
    const float dinv = 1.0f / (float)(d > 1 ? d : 1);

    int mycol = 0;
    if (lane < cnt) mycol = nbr[(size_t)row * MAX_NBR + lane];

    if (wave == 0) {
        if constexpr (KPL == 2) {
            const float2 f = *(const float2*)(hin + (size_t)row * D_IN + 2 * lane);
            s_self[2 * lane] = f.x; s_self[2 * lane + 1] = f.y;
        } else {
            if (lane < D_IN) s_self[lane] = hin[(size_t)row * D_IN + lane];
        }
    }

    float nv[KPL];
    #pragma unroll
    for (int i = 0; i < KPL; ++i) nv[i] = 0.f;
    for (int t = strm; t < cnt; t += NW) {
        const int j = jbase + __shfl(mycol, t, 64);
        if constexpr (KPL == 2) {
            const float2 f = *(const float2*)(hin + (size_t)j * D_IN + 2 * lane);
            nv[0] += f.x; nv[1] += f.y;
        } else {
            nv[0] += hin[(size_t)j * D_IN + sl];
        }
    }
    if constexpr (KPL == 2) {
        s_part[strm][2 * lane]     = nv[0];
        s_part[strm][2 * lane + 1] = nv[1];
    } else {
        s_part[strm][sl] = nv[0];
    }
    __syncthreads();

    if (tid < D_IN) {
        float s = 0.f;
        #pragma unroll
        for (int p = 0; p < NW; ++p) s += s_part[p][tid];
        s_neigh[tid] = s * dinv;
    }
    __syncthreads();

    if (wave == 0) {
        constexpr int SEG  = 64 / D_OUT;
        constexpr int KSEG = D_IN / SEG;
        const int o = lane % D_OUT, seg = lane / D_OUT;
        float acc = 0.f;
        #pragma unroll 8
        for (int kk = 0; kk < KSEG; ++kk) {
            const int k = seg * KSEG + kk;
            acc = fmaf(s_self[k],  Ws[k * D_OUT + o], acc);
            acc = fmaf(s_neigh[k], Wn[k * D_OUT + o], acc);
        }
        if constexpr (SEG == 2) acc += __shfl_xor(acc, 32, 64);
        if (seg == 0)
            hout[(size_t)row * D_OUT + o] = fmaxf(acc + bias[o], 0.f);
    }
}

extern "C" void kernel_launch(void* const* d_in, const int* in_sizes, int n_in,
                              void* d_out, int out_size, void* d_ws, size_t ws_size,
                              hipStream_t stream) {
    const float* x   = (const float*)d_in[0];
    const float* adj = (const float*)d_in[1];
    const float* Ws0 = (const float*)d_in[2]; const float* Wn0 = (const float*)d_in[3];
    const float* b0  = (const float*)d_in[4];
    const float* Ws1 = (const float*)d_in[5]; const float* Wn1 = (const float*)d_in[6];
    const float* b1  = (const float*)d_in[7];
    const float* Ws2 = (const float*)d_in[8]; const float* Wn2 = (const float*)d_in[9];
    const float* b2  = (const float*)d_in[10];

    char* ws = (char*)d_ws;
    unsigned short* nbr = (unsigned short*)(ws + WS_NBR);
    int*   deg = (int*)(ws + WS_DEG);
    float* h0  = (float*)(ws + WS_H0);
    float* h1  = (float*)(ws + WS_H1);

    // Pipeline launched TWICE (idempotent) — second pass recomputes identical
    // values; dur delta vs R12 isolates total kernel time K from harness resets.
    for (int rep = 0; rep < 2; ++rep) {
        build_csr_kernel<<<BN / 4, 256, 0, stream>>>(adj, nbr, deg);
        gather_layer_kernel<128, 64><<<BN, 256, 0, stream>>>(
            x,  nbr, deg, Ws0, Wn0, b0, h0);
        gather_layer_kernel<64, 32><<<BN, 256, 0, stream>>>(
            h0, nbr, deg, Ws1, Wn1, b1, h1);
        gather_layer_kernel<32, 32><<<BN, 256, 0, stream>>>(
            h1, nbr, deg, Ws2, Wn2, b2, (float*)d_out);
    }
}

// Round 14
// 863.607 us; speedup vs baseline: 1.4088x; 1.4088x over previous
//
#include <hip/hip_runtime.h>
#include <hip/hip_bf16.h>

#define BN      32768   // B*N rows
#define NCOL    4096    // N
#define MAX_NBR 64      // Binomial(4096,0.004): mean 16.4, P(deg>64) ~ 1e-19

// ws layout (bytes) — ws_size ~2 GB; 16.3 MB used
#define WS_NBR 0                       // u16 [BN][64]   (4 MB)
#define WS_DEG (4*1024*1024)           // int [BN]       (128 KB)
#define WS_H0  (WS_DEG + 131072)       // f32 [BN][64]   (8 MB)
#define WS_H1  (WS_H0 + 8*1024*1024)   // f32 [BN][32]   (4 MB)

// ---------- kernel 1: one-pass CSR build, streaming-optimized ----------
// Old version: 64 ballot+popcount rounds + 64 divergent scattered u16 global
// stores per row -> ~2 TB/s. New: bit-OR test per float4 chunk (98.4% skip on
// one branch), rare LDS-atomic append (~16/row), coalesced flush. adj values
// are exactly {0.0f, 1.0f} (R8 probe) -> integer bit test is exact.
__global__ __launch_bounds__(256) void build_csr_kernel(
    const float* __restrict__ adj,
    unsigned short* __restrict__ nbr,   // [BN][MAX_NBR] col indices (any order: mean)
    int* __restrict__ deg)              // [BN] exact row one-count
{
    __shared__ int s_cnt[4];
    __shared__ unsigned short s_list[4][MAX_NBR];
    const int wave = threadIdx.x >> 6, lane = threadIdx.x & 63;
    const int row  = (blockIdx.x << 2) + wave;
    if (lane == 0) s_cnt[wave] = 0;
    __syncthreads();

    const uint4* arow = reinterpret_cast<const uint4*>(adj + (size_t)row * NCOL);
    #pragma unroll
    for (int t = 0; t < 16; ++t) {      // 16 independent 16B loads in flight
        const uint4 q = arow[t * 64 + lane];
        if (q.x | q.y | q.z | q.w) {    // ~1 active lane/wave/iter
            const int c4 = (t * 64 + lane) * 4;
            if (q.x) { int p = atomicAdd(&s_cnt[wave], 1);
                       if (p < MAX_NBR) s_list[wave][p] = (unsigned short)(c4    ); }
            if (q.y) { int p = atomicAdd(&s_cnt[wave], 1);
                       if (p < MAX_NBR) s_list[wave][p] = (unsigned short)(c4 + 1); }
            if (q.z) { int p = atomicAdd(&s_cnt[wave], 1);
                       if (p < MAX_NBR) s_list[wave][p] = (unsigned short)(c4 + 2); }
            if (q.w) { int p = atomicAdd(&s_cnt[wave], 1);
                       if (p < MAX_NBR) s_list[wave][p] = (unsigned short)(c4 + 3); }
        }
    }
    __syncthreads();
    const int cnt = s_cnt[wave];
    const int cl  = cnt < MAX_NBR ? cnt : MAX_NBR;
    if (lane < cl) nbr[(size_t)row * MAX_NBR + lane] = s_list[wave][lane];
    if (lane == 0) deg[row] = cnt;
}

// ---------- kernels 2-4: gather + GEMV, one block per row, XCD-SWIZZLED ----------
// row = (blk%8)*4096 + blk/8: batch k pins to XCD k (8 batches, 8 XCDs), so all
// gathers for a batch hit that XCD's 4 MB L2 (slice is 2 MB for x, less for h).
template<int D_IN, int D_OUT>
__global__ __launch_bounds__(256) void gather_layer_kernel(
    const float* __restrict__ hin,      // [BN][D_IN]
    const unsigned short* __restrict__ nbr,
    const int* __restrict__ deg,
    const float* __restrict__ Ws, const float* __restrict__ Wn,   // [D_IN][D_OUT]
    const float* __restrict__ bias,
    float* __restrict__ hout)           // [BN][D_OUT] fp32
{
    constexpr int SUB = (D_IN >= 64) ? 1 : (64 / D_IN);  // subwave streams per wave
    constexpr int KPL = (D_IN + 63) / 64;                // floats/lane (2 iff D_IN=128)
    constexpr int NW  = 4 * SUB;                         // total gather streams
    __shared__ float s_self[D_IN];
    __shared__ float s_part[NW][D_IN];
    __shared__ float s_neigh[D_IN];

    const int tid  = threadIdx.x;
    const int wave = tid >> 6, lane = tid & 63;
    const int sub  = (D_IN < 64) ? (lane / D_IN) : 0;
    const int sl   = (D_IN < 64) ? (lane % D_IN) : lane;
    const int strm = wave * SUB + sub;
    // XCD-locality swizzle: batch = blk & 7 -> all of batch k on XCD k
    const int row  = ((blockIdx.x & 7) << 12) | (blockIdx.x >> 3);
    const int jbase = row & ~(NCOL - 1);                 // b*N

    const int d   = deg[row];
    const int cnt = d < MAX_NBR ? d : MAX_NBR;
    const float dinv = 1.0f / (float)(d > 1 ? d : 1);

    int mycol = 0;
    if (lane < cnt) mycol = nbr[(size_t)row * MAX_NBR + lane];

    if (wave == 0) {
        if constexpr (KPL == 2) {
            const float2 f = *(const float2*)(hin + (size_t)row * D_IN + 2 * lane);
            s_self[2 * lane] = f.x; s_self[2 * lane + 1] = f.y;
        } else {
            if (lane < D_IN) s_self[lane] = hin[(size_t)row * D_IN + lane];
        }
    }

    float nv[KPL];
    #pragma unroll
    for (int i = 0; i < KPL; ++i) nv[i] = 0.f;
    for (int t = strm; t < cnt; t += NW) {
        const int j = jbase + __shfl(mycol, t, 64);
        if constexpr (KPL == 2) {
            const float2 f = *(const float2*)(hin + (size_t)j * D_IN + 2 * lane);
            nv[0] += f.x; nv[1] += f.y;
        } else {
            nv[0] += hin[(size_t)j * D_IN + sl];
        }
    }
    if constexpr (KPL == 2) {
        s_part[strm][2 * lane]     = nv[0];
        s_part[strm][2 * lane + 1] = nv[1];
    } else {
        s_part[strm][sl] = nv[0];
    }
    __syncthreads();

    if (tid < D_IN) {
        float s = 0.f;
        #pragma unroll
        for (int p = 0; p < NW; ++p) s += s_part[p][tid];
        s_neigh[tid] = s * dinv;
    }
    __syncthreads();

    if (wave == 0) {
        constexpr int SEG  = 64 / D_OUT;
        constexpr int KSEG = D_IN / SEG;
        const int o = lane % D_OUT, seg = lane / D_OUT;
        float acc = 0.f;
        #pragma unroll 8
        for (int kk = 0; kk < KSEG; ++kk) {
            const int k = seg * KSEG + kk;
            acc = fmaf(s_self[k],  Ws[k * D_OUT + o], acc);
            acc = fmaf(s_neigh[k], Wn[k * D_OUT + o], acc);
        }
        if constexpr (SEG == 2) acc += __shfl_xor(acc, 32, 64);
        if (seg == 0)
            hout[(size_t)row * D_OUT + o] = fmaxf(acc + bias[o], 0.f);
    }
}

extern "C" void kernel_launch(void* const* d_in, const int* in_sizes, int n_in,
                              void* d_out, int out_size, void* d_ws, size_t ws_size,
                              hipStream_t stream) {
    // x, adj, Ws0, Wn0, b0, Ws1, Wn1, b1, Ws2, Wn2, b2 — all fp32; d_out fp32
    const float* x   = (const float*)d_in[0];
    const float* adj = (const float*)d_in[1];
    const float* Ws0 = (const float*)d_in[2]; const float* Wn0 = (const float*)d_in[3];
    const float* b0  = (const float*)d_in[4];
    const float* Ws1 = (const float*)d_in[5]; const float* Wn1 = (const float*)d_in[6];
    const float* b1  = (const float*)d_in[7];
    const float* Ws2 = (const float*)d_in[8]; const float* Wn2 = (const float*)d_in[9];
    const float* b2  = (const float*)d_in[10];

    char* ws = (char*)d_ws;
    unsigned short* nbr = (unsigned short*)(ws + WS_NBR);
    int*   deg = (int*)(ws + WS_DEG);
    float* h0  = (float*)(ws + WS_H0);
    float* h1  = (float*)(ws + WS_H1);

    build_csr_kernel<<<BN / 4, 256, 0, stream>>>(adj, nbr, deg);
    gather_layer_kernel<128, 64><<<BN, 256, 0, stream>>>(
        x,  nbr, deg, Ws0, Wn0, b0, h0);
    gather_layer_kernel<64, 32><<<BN, 256, 0, stream>>>(
        h0, nbr, deg, Ws1, Wn1, b1, h1);
    gather_layer_kernel<32, 32><<<BN, 256, 0, stream>>>(
        h1, nbr, deg, Ws2, Wn2, b2, (float*)d_out);
}

// Round 15
// 836.369 us; speedup vs baseline: 1.4547x; 1.0326x over previous
//
#include <hip/hip_runtime.h>
#include <hip/hip_bf16.h>

#define BN      32768   // B*N rows
#define NCOL    4096    // N
#define MAX_NBR 64      // Binomial(4096,0.004): mean 16.4, P(deg>64) ~ 1e-19

// ws layout (bytes) — ws_size ~2 GB; 16.3 MB used
#define WS_NBR 0                       // u16 [BN][64]   (4 MB)
#define WS_DEG (4*1024*1024)           // int [BN]       (128 KB)
#define WS_H0  (WS_DEG + 131072)       // f32 [BN][64]   (8 MB)
#define WS_H1  (WS_H0 + 8*1024*1024)   // f32 [BN][32]   (4 MB)

typedef unsigned int u32x4 __attribute__((ext_vector_type(4)));

// ---------- kernel 1: FUSED adj-scan + CSR write + SAGE layer 0 ----------
// One wave per row, 4 rows/block, XCD-swizzled (batch k -> XCD k). The adj
// stream uses non-temporal loads so the x slice (2 MB/batch) stays L2-resident
// for the fused gathers. Layer-0 work hides inside the mandatory 512 MB read.
__global__ __launch_bounds__(256) void fused_csr_layer0_kernel(
    const float* __restrict__ adj,
    const float* __restrict__ x,        // [BN][128]
    const float* __restrict__ Ws, const float* __restrict__ Wn,   // [128][64]
    const float* __restrict__ bias,     // [64]
    unsigned short* __restrict__ nbr,   // [BN][MAX_NBR] (for layers 1,2)
    int* __restrict__ deg,              // [BN]
    float* __restrict__ h0)             // [BN][64]
{
    __shared__ int s_cnt[4];
    __shared__ unsigned short s_list[4][MAX_NBR];
    __shared__ float s_self[4][128];
    __shared__ float s_neigh[4][128];

    const int wave = threadIdx.x >> 6, lane = threadIdx.x & 63;
    // batch = blk & 7 pins to XCD; 4 consecutive rows per block within batch
    const int row  = (((blockIdx.x & 7) << 12) | ((blockIdx.x >> 3) << 2)) + wave;
    const int jbase = row & ~(NCOL - 1);       // b*N

    if (lane == 0) s_cnt[wave] = 0;
    __syncthreads();

    // ---- adj scan (non-temporal stream; values exactly {0f,1f} per R8 probe) ----
    const u32x4* arow = reinterpret_cast<const u32x4*>(adj + (size_t)row * NCOL);
    #pragma unroll
    for (int t = 0; t < 16; ++t) {
        const u32x4 q = __builtin_nontemporal_load(&arow[t * 64 + lane]);
        if (q.x | q.y | q.z | q.w) {           // ~1 active lane/wave/iter
            const int c4 = (t * 64 + lane) * 4;
            if (q.x) { int p = atomicAdd(&s_cnt[wave], 1);
                       if (p < MAX_NBR) s_list[wave][p] = (unsigned short)(c4    ); }
            if (q.y) { int p = atomicAdd(&s_cnt[wave], 1);
                       if (p < MAX_NBR) s_list[wave][p] = (unsigned short)(c4 + 1); }
            if (q.z) { int p = atomicAdd(&s_cnt[wave], 1);
                       if (p < MAX_NBR) s_list[wave][p] = (unsigned short)(c4 + 2); }
            if (q.w) { int p = atomicAdd(&s_cnt[wave], 1);
                       if (p < MAX_NBR) s_list[wave][p] = (unsigned short)(c4 + 3); }
        }
    }
    __syncthreads();

    const int d   = s_cnt[wave];
    const int cnt = d < MAX_NBR ? d : MAX_NBR;
    const float dinv = 1.0f / (float)(d > 1 ? d : 1);

    // flush CSR for layers 1,2
    if (lane < cnt) nbr[(size_t)row * MAX_NBR + lane] = s_list[wave][lane];
    if (lane == 0) deg[row] = d;

    // ---- layer 0: gather x neighbors (L2-hot), mean, GEMV ----
    const float2 sf = *(const float2*)(x + (size_t)row * 128 + 2 * lane);
    float n0 = 0.f, n1 = 0.f;
    for (int t = 0; t < cnt; ++t) {
        const int j = jbase + (int)s_list[wave][t];       // LDS broadcast
        const float2 f = *(const float2*)(x + (size_t)j * 128 + 2 * lane);
        n0 += f.x; n1 += f.y;
    }
    s_self[wave][2 * lane]      = sf.x;
    s_self[wave][2 * lane + 1]  = sf.y;
    s_neigh[wave][2 * lane]     = n0 * dinv;
    s_neigh[wave][2 * lane + 1] = n1 * dinv;
    // per-wave data, no cross-wave deps: LDS writes by this wave are visible to
    // its own later reads in program order (single-wave ordering).

    const int o = lane;                                   // D_OUT = 64
    float acc = 0.f;
    #pragma unroll 8
    for (int k = 0; k < 128; ++k) {
        acc = fmaf(s_self[wave][k],  Ws[k * 64 + o], acc);
        acc = fmaf(s_neigh[wave][k], Wn[k * 64 + o], acc);
    }
    h0[(size_t)row * 64 + o] = fmaxf(acc + bias[o], 0.f);
}

// ---------- layers 1,2: gather + GEMV, one block per row, XCD-swizzled ----------
template<int D_IN, int D_OUT>
__global__ __launch_bounds__(256) void gather_layer_kernel(
    const float* __restrict__ hin,
    const unsigned short* __restrict__ nbr,
    const int* __restrict__ deg,
    const float* __restrict__ Ws, const float* __restrict__ Wn,   // [D_IN][D_OUT]
    const float* __restrict__ bias,
    float* __restrict__ hout)
{
    constexpr int SUB = (D_IN >= 64) ? 1 : (64 / D_IN);
    constexpr int KPL = (D_IN + 63) / 64;
    constexpr int NW  = 4 * SUB;
    __shared__ float s_self[D_IN];
    __shared__ float s_part[NW][D_IN];
    __shared__ float s_neigh[D_IN];

    const int tid  = threadIdx.x;
    const int wave = tid >> 6, lane = tid & 63;
    const int sub  = (D_IN < 64) ? (lane / D_IN) : 0;
    const int sl   = (D_IN < 64) ? (lane % D_IN) : lane;
    const int strm = wave * SUB + sub;
    const int row  = ((blockIdx.x & 7) << 12) | (blockIdx.x >> 3);  // XCD swizzle
    const int jbase = row & ~(NCOL - 1);

    const int d   = deg[row];
    const int cnt = d < MAX_NBR ? d : MAX_NBR;
    const float dinv = 1.0f / (float)(d > 1 ? d : 1);

    int mycol = 0;
    if (lane < cnt) mycol = nbr[(size_t)row * MAX_NBR + lane];

    if (wave == 0) {
        if constexpr (KPL == 2) {
            const float2 f = *(const float2*)(hin + (size_t)row * D_IN + 2 * lane);
            s_self[2 * lane] = f.x; s_self[2 * lane + 1] = f.y;
        } else {
            if (lane < D_IN) s_self[lane] = hin[(size_t)row * D_IN + lane];
        }
    }

    float nv[KPL];
    #pragma unroll
    for (int i = 0; i < KPL; ++i) nv[i] = 0.f;
    for (int t = strm; t < cnt; t += NW) {
        const int j = jbase + __shfl(mycol, t, 64);
        if constexpr (KPL == 2) {
            const float2 f = *(const float2*)(hin + (size_t)j * D_IN + 2 * lane);
            nv[0] += f.x; nv[1] += f.y;
        } else {
            nv[0] += hin[(size_t)j * D_IN + sl];
        }
    }
    if constexpr (KPL == 2) {
        s_part[strm][2 * lane]     = nv[0];
        s_part[strm][2 * lane + 1] = nv[1];
    } else {
        s_part[strm][sl] = nv[0];
    }
    __syncthreads();

    if (tid < D_IN) {
        float s = 0.f;
        #pragma unroll
        for (int p = 0; p < NW; ++p) s += s_part[p][tid];
        s_neigh[tid] = s * dinv;
    }
    __syncthreads();

    if (wave == 0) {
        constexpr int SEG  = 64 / D_OUT;
        constexpr int KSEG = D_IN / SEG;
        const int o = lane % D_OUT, seg = lane / D_OUT;
        float acc = 0.f;
        #pragma unroll 8
        for (int kk = 0; kk < KSEG; ++kk) {
            const int k = seg * KSEG + kk;
            acc = fmaf(s_self[k],  Ws[k * D_OUT + o], acc);
            acc = fmaf(s_neigh[k], Wn[k * D_OUT + o], acc);
        }
        if constexpr (SEG == 2) acc += __shfl_xor(acc, 32, 64);
        if (seg == 0)
            hout[(size_t)row * D_OUT + o] = fmaxf(acc + bias[o], 0.f);
    }
}

extern "C" void kernel_launch(void* const* d_in, const int* in_sizes, int n_in,
                              void* d_out, int out_size, void* d_ws, size_t ws_size,
                              hipStream_t stream) {
    // x, adj, Ws0, Wn0, b0, Ws1, Wn1, b1, Ws2, Wn2, b2 — all fp32; d_out fp32
    const float* x   = (const float*)d_in[0];
    const float* adj = (const float*)d_in[1];
    const float* Ws0 = (const float*)d_in[2]; const float* Wn0 = (const float*)d_in[3];
    const float* b0  = (const float*)d_in[4];
    const float* Ws1 = (const float*)d_in[5]; const float* Wn1 = (const float*)d_in[6];
    const float* b1  = (const float*)d_in[7];
    const float* Ws2 = (const float*)d_in[8]; const float* Wn2 = (const float*)d_in[9];
    const float* b2  = (const float*)d_in[10];

    char* ws = (char*)d_ws;
    unsigned short* nbr = (unsigned short*)(ws + WS_NBR);
    int*   deg = (int*)(ws + WS_DEG);
    float* h0  = (float*)(ws + WS_H0);
    float* h1  = (float*)(ws + WS_H1);

    fused_csr_layer0_kernel<<<BN / 4, 256, 0, stream>>>(
        adj, x, Ws0, Wn0, b0, nbr, deg, h0);
    gather_layer_kernel<64, 32><<<BN, 256, 0, stream>>>(
        h0, nbr, deg, Ws1, Wn1, b1, h1);
    gather_layer_kernel<32, 32><<<BN, 256, 0, stream>>>(
        h1, nbr, deg, Ws2, Wn2, b2, (float*)d_out);
}